// Round 1
// baseline (1738.585 us; speedup 1.0000x reference)
//
#include <hip/hip_runtime.h>

// ---------------------------------------------------------------------------
// GCN forward: 4 layers (128->64->64->64->32), N=100000 nodes, E=1600000 edges
// Pipeline per layer:  h = in @ W   (gemm_kernel, ReLU fused on input read)
//                      out = b + dinv^2 * h          (init_out_kernel, full overwrite)
//                      out[col] += h[row]*dinv[row]*dinv[col]  (agg_kernel, atomics)
// ---------------------------------------------------------------------------

__global__ __launch_bounds__(256) void deg_init_kernel(float* __restrict__ deg, int N) {
    int i = blockIdx.x * blockDim.x + threadIdx.x;
    if (i < N) deg[i] = 1.0f;  // self-loop contributes 1 to every node's degree
}

__global__ __launch_bounds__(256) void deg_acc_kernel(const int* __restrict__ col,
                                                      float* __restrict__ deg, int E) {
    int e = blockIdx.x * blockDim.x + threadIdx.x;
    if (e < E) atomicAdd(&deg[col[e]], 1.0f);
}

__global__ __launch_bounds__(256) void dinv_kernel(float* __restrict__ deg, int N) {
    int i = blockIdx.x * blockDim.x + threadIdx.x;
    if (i < N) deg[i] = 1.0f / sqrtf(deg[i]);  // deg >= 1 always (self-loop)
}

// h[r, 0:F_OUT] = (RELU? relu(in) : in)[r, :] @ W ; W is [F_IN, F_OUT] row-major.
// One SUB-lane segment per row; lane sl computes output feature sl.
template <int F_IN, int F_OUT, bool RELU>
__global__ __launch_bounds__(256) void gemm_kernel(const float* __restrict__ in,
                                                   const float* __restrict__ W,
                                                   float* __restrict__ out, int N) {
    constexpr int SUB = F_OUT;       // 64 or 32 lanes per row
    constexpr int NV  = F_IN / SUB;  // input values held per lane
    constexpr int GPB = 256 / SUB;   // rows per block
    __shared__ float sW[F_IN * F_OUT];
    for (int i = threadIdx.x; i < F_IN * F_OUT; i += 256) sW[i] = W[i];
    __syncthreads();

    const int grp = threadIdx.x / SUB;
    const int sl  = threadIdx.x % SUB;
    const int r   = blockIdx.x * GPB + grp;
    if (r >= N) return;

    float inv[NV];
#pragma unroll
    for (int t = 0; t < NV; ++t) {
        float v = in[r * F_IN + t * SUB + sl];
        inv[t] = RELU ? fmaxf(v, 0.0f) : v;
    }
    float acc = 0.0f;
#pragma unroll
    for (int k = 0; k < F_IN; ++k) {
        float xv = __shfl(inv[k / SUB], k % SUB, SUB);  // broadcast in[r][k] in segment
        acc = fmaf(xv, sW[k * F_OUT + sl], acc);
    }
    out[r * F_OUT + sl] = acc;
}

// out[i, j] = b[j] + dinv[i]^2 * h[i, j]   (bias + self-loop message, full overwrite)
template <int F>
__global__ __launch_bounds__(256) void init_out_kernel(const float* __restrict__ h,
                                                       const float* __restrict__ b,
                                                       const float* __restrict__ dinv,
                                                       float* __restrict__ out, int N) {
    int tid = blockIdx.x * blockDim.x + threadIdx.x;
    if (tid >= N * F) return;
    int i = tid / F;
    int j = tid % F;
    float d = dinv[i];
    out[tid] = b[j] + d * d * h[tid];
}

// out[col[e], j] += h[row[e], j] * dinv[row[e]] * dinv[col[e]]
template <int F>
__global__ __launch_bounds__(256) void agg_kernel(const float* __restrict__ h,
                                                  const int* __restrict__ row,
                                                  const int* __restrict__ col,
                                                  const float* __restrict__ dinv,
                                                  float* __restrict__ out, int E) {
    int tid = blockIdx.x * blockDim.x + threadIdx.x;
    int e = tid / F;
    if (e >= E) return;
    int j = tid % F;
    int r = row[e];
    int c = col[e];
    float nrm = dinv[r] * dinv[c];
    atomicAdd(&out[c * F + j], h[r * F + j] * nrm);
}

extern "C" void kernel_launch(void* const* d_in, const int* in_sizes, int n_in,
                              void* d_out, int out_size, void* d_ws, size_t ws_size,
                              hipStream_t stream) {
    const float* x  = (const float*)d_in[0];
    const int*   ei = (const int*)d_in[1];
    const float* W1 = (const float*)d_in[2];
    const float* b1 = (const float*)d_in[3];
    const float* W2 = (const float*)d_in[4];
    const float* b2 = (const float*)d_in[5];
    const float* W3 = (const float*)d_in[6];
    const float* b3 = (const float*)d_in[7];
    const float* W4 = (const float*)d_in[8];
    const float* b4 = (const float*)d_in[9];

    const int N = in_sizes[0] / 128;  // 100000
    const int E = in_sizes[1] / 2;    // 1600000
    const int* row = ei;              // edge_index[0] = source
    const int* col = ei + E;          // edge_index[1] = destination

    float* dinv = (float*)d_ws;            // N floats (also used as deg)
    float* hA   = dinv + N;                // N*64 floats (gemm output)
    float* hB   = hA + (size_t)N * 64;     // N*64 floats (aggregated output)
    float* out  = (float*)d_out;           // N*32 floats

    const int T = 256;

    // ---- gcn_norm: dinv = 1/sqrt(deg) with self-loops -----------------------
    deg_init_kernel<<<(N + T - 1) / T, T, 0, stream>>>(dinv, N);
    deg_acc_kernel<<<(E + T - 1) / T, T, 0, stream>>>(col, dinv, E);
    dinv_kernel<<<(N + T - 1) / T, T, 0, stream>>>(dinv, N);

    const int gemm64_blocks = (N + 3) / 4;   // 4 rows/block (SUB=64)
    const int gemm32_blocks = (N + 7) / 8;   // 8 rows/block (SUB=32)
    const long long nf64 = (long long)N * 64;
    const long long ef64 = (long long)E * 64;
    const long long nf32 = (long long)N * 32;
    const long long ef32 = (long long)E * 32;

    // ---- layer 1: x[128] -> 64 ---------------------------------------------
    gemm_kernel<128, 64, false><<<gemm64_blocks, T, 0, stream>>>(x, W1, hA, N);
    init_out_kernel<64><<<(nf64 + T - 1) / T, T, 0, stream>>>(hA, b1, dinv, hB, N);
    agg_kernel<64><<<(ef64 + T - 1) / T, T, 0, stream>>>(hA, row, col, dinv, hB, E);

    // ---- layer 2: relu(hB)[64] -> 64 ---------------------------------------
    gemm_kernel<64, 64, true><<<gemm64_blocks, T, 0, stream>>>(hB, W2, hA, N);
    init_out_kernel<64><<<(nf64 + T - 1) / T, T, 0, stream>>>(hA, b2, dinv, hB, N);
    agg_kernel<64><<<(ef64 + T - 1) / T, T, 0, stream>>>(hA, row, col, dinv, hB, E);

    // ---- layer 3: relu(hB)[64] -> 64 ---------------------------------------
    gemm_kernel<64, 64, true><<<gemm64_blocks, T, 0, stream>>>(hB, W3, hA, N);
    init_out_kernel<64><<<(nf64 + T - 1) / T, T, 0, stream>>>(hA, b3, dinv, hB, N);
    agg_kernel<64><<<(ef64 + T - 1) / T, T, 0, stream>>>(hA, row, col, dinv, hB, E);

    // ---- layer 4: relu(hB)[64] -> 32, straight into d_out (no ReLU) --------
    gemm_kernel<64, 32, true><<<gemm32_blocks, T, 0, stream>>>(hB, W4, hA, N);
    init_out_kernel<32><<<(nf32 + T - 1) / T, T, 0, stream>>>(hA, b4, dinv, out, N);
    agg_kernel<32><<<(ef32 + T - 1) / T, T, 0, stream>>>(hA, row, col, dinv, out, E);
}

// Round 2
// 943.082 us; speedup vs baseline: 1.8435x; 1.8435x over previous
//
#include <hip/hip_runtime.h>

// ---------------------------------------------------------------------------
// GCN forward, CSR-based. N=100000 nodes, E=1600000 edges.
//   build CSR by destination (once):  cnt -> scan -> scatter
//   per layer:  H = (relu?)(X) @ W * dinv[row]        (gemm_kernel)
//               X[c] = b + dinv[c]*(sum_{r in N(c)} H[r] + H[c])   (agg_csr)
// ---------------------------------------------------------------------------

__global__ __launch_bounds__(256) void zero_i32_kernel(int* __restrict__ p, int n) {
    int i = blockIdx.x * blockDim.x + threadIdx.x;
    if (i < n) p[i] = 0;
}

__global__ __launch_bounds__(256) void hist_kernel(const int* __restrict__ col,
                                                   int* __restrict__ cnt, int E) {
    int e = blockIdx.x * blockDim.x + threadIdx.x;
    if (e < E) atomicAdd(&cnt[col[e]], 1);
}

__global__ __launch_bounds__(256) void dinv_kernel(const int* __restrict__ cnt,
                                                   float* __restrict__ dinv, int N) {
    int i = blockIdx.x * blockDim.x + threadIdx.x;
    if (i < N) dinv[i] = rsqrtf((float)cnt[i] + 1.0f);  // +1 self-loop
}

__global__ __launch_bounds__(256) void block_reduce_kernel(const int* __restrict__ cnt,
                                                           int* __restrict__ bsum, int N) {
    __shared__ int s[256];
    int i = blockIdx.x * 256 + threadIdx.x;
    s[threadIdx.x] = (i < N) ? cnt[i] : 0;
    __syncthreads();
    for (int off = 128; off > 0; off >>= 1) {
        if (threadIdx.x < off) s[threadIdx.x] += s[threadIdx.x + off];
        __syncthreads();
    }
    if (threadIdx.x == 0) bsum[blockIdx.x] = s[0];
}

// single block of 512 threads, exclusive-scans bsum in place (nb <= 512)
__global__ __launch_bounds__(512) void scan_bsums_kernel(int* __restrict__ bsum, int nb) {
    __shared__ int s[512];
    int tid = threadIdx.x;
    int v = (tid < nb) ? bsum[tid] : 0;
    s[tid] = v;
    __syncthreads();
    for (int off = 1; off < 512; off <<= 1) {
        int t = (tid >= off) ? s[tid - off] : 0;
        __syncthreads();
        s[tid] += t;
        __syncthreads();
    }
    if (tid < nb) bsum[tid] = s[tid] - v;  // exclusive
}

__global__ __launch_bounds__(256) void scan_kernel(const int* __restrict__ cnt,
                                                   const int* __restrict__ bsum,
                                                   int* __restrict__ offs, int N) {
    __shared__ int s[256];
    int i = blockIdx.x * 256 + threadIdx.x;
    int v = (i < N) ? cnt[i] : 0;
    s[threadIdx.x] = v;
    __syncthreads();
    for (int off = 1; off < 256; off <<= 1) {
        int t = (threadIdx.x >= off) ? s[threadIdx.x - off] : 0;
        __syncthreads();
        s[threadIdx.x] += t;
        __syncthreads();
    }
    int excl = s[threadIdx.x] - v + bsum[blockIdx.x];
    if (i < N) offs[i] = excl;
    if (i == N - 1) offs[N] = excl + v;
}

__global__ __launch_bounds__(256) void copy_i32_kernel(const int* __restrict__ src,
                                                       int* __restrict__ dst, int n) {
    int i = blockIdx.x * blockDim.x + threadIdx.x;
    if (i < n) dst[i] = src[i];
}

__global__ __launch_bounds__(256) void scatter_kernel(const int* __restrict__ row,
                                                      const int* __restrict__ col,
                                                      int* __restrict__ cursor,
                                                      int* __restrict__ eidx, int E) {
    int e = blockIdx.x * blockDim.x + threadIdx.x;
    if (e < E) {
        int pos = atomicAdd(&cursor[col[e]], 1);
        eidx[pos] = row[e];
    }
}

// H[r, 0:F_OUT] = ((RELU? relu(in) : in)[r, :] @ W) * dinv[r]
template <int F_IN, int F_OUT, bool RELU>
__global__ __launch_bounds__(256) void gemm_kernel(const float* __restrict__ in,
                                                   const float* __restrict__ W,
                                                   const float* __restrict__ dinv,
                                                   float* __restrict__ out, int N) {
    constexpr int SUB = F_OUT;
    constexpr int NV  = F_IN / SUB;
    constexpr int GPB = 256 / SUB;
    __shared__ float sW[F_IN * F_OUT];
    for (int i = threadIdx.x; i < F_IN * F_OUT; i += 256) sW[i] = W[i];
    __syncthreads();

    const int grp = threadIdx.x / SUB;
    const int sl  = threadIdx.x % SUB;
    const int r   = blockIdx.x * GPB + grp;
    if (r >= N) return;

    float inv[NV];
#pragma unroll
    for (int t = 0; t < NV; ++t) {
        float v = in[(size_t)r * F_IN + t * SUB + sl];
        inv[t] = RELU ? fmaxf(v, 0.0f) : v;
    }
    float acc = 0.0f;
#pragma unroll
    for (int k = 0; k < F_IN; ++k) {
        float xv = __shfl(inv[k / SUB], k % SUB, SUB);
        acc = fmaf(xv, sW[k * F_OUT + sl], acc);
    }
    out[(size_t)r * F_OUT + sl] = acc * dinv[r];
}

// out[c, j] = b[j] + dinv[c] * ( sum_{k in [offs[c],offs[c+1])} H[eidx[k], j] + H[c, j] )
template <int F>
__global__ __launch_bounds__(256) void agg_csr_kernel(const float* __restrict__ h,
                                                      const int* __restrict__ offs,
                                                      const int* __restrict__ eidx,
                                                      const float* __restrict__ dinv,
                                                      const float* __restrict__ b,
                                                      float* __restrict__ out, int N) {
    int seg = (blockIdx.x * 256 + threadIdx.x) / F;  // destination node
    int j   = threadIdx.x % F;
    if (seg >= N) return;
    int s = offs[seg];
    int e = offs[seg + 1];

    float a0 = 0.f, a1 = 0.f, a2 = 0.f, a3 = 0.f;
    int k = s;
    for (; k + 4 <= e; k += 4) {
        int r0 = eidx[k], r1 = eidx[k + 1], r2 = eidx[k + 2], r3 = eidx[k + 3];
        a0 += h[(size_t)r0 * F + j];
        a1 += h[(size_t)r1 * F + j];
        a2 += h[(size_t)r2 * F + j];
        a3 += h[(size_t)r3 * F + j];
    }
    for (; k < e; ++k) a0 += h[(size_t)eidx[k] * F + j];

    float acc  = (a0 + a1) + (a2 + a3);
    float self = h[(size_t)seg * F + j];
    out[(size_t)seg * F + j] = b[j] + dinv[seg] * (acc + self);
}

extern "C" void kernel_launch(void* const* d_in, const int* in_sizes, int n_in,
                              void* d_out, int out_size, void* d_ws, size_t ws_size,
                              hipStream_t stream) {
    const float* x  = (const float*)d_in[0];
    const int*   ei = (const int*)d_in[1];
    const float* W1 = (const float*)d_in[2];
    const float* b1 = (const float*)d_in[3];
    const float* W2 = (const float*)d_in[4];
    const float* b2 = (const float*)d_in[5];
    const float* W3 = (const float*)d_in[6];
    const float* b3 = (const float*)d_in[7];
    const float* W4 = (const float*)d_in[8];
    const float* b4 = (const float*)d_in[9];

    const int N = in_sizes[0] / 128;  // 100000
    const int E = in_sizes[1] / 2;    // 1600000
    const int* row = ei;              // source
    const int* col = ei + E;          // destination

    // ---- workspace layout ---------------------------------------------------
    char* w = (char*)d_ws;
    int*   cnt    = (int*)w;                 w += (size_t)N * 4;
    int*   offs   = (int*)w;                 w += (size_t)(N + 1) * 4;
    int*   cursor = (int*)w;                 w += (size_t)N * 4;
    int*   bsum   = (int*)w;                 w += 512 * 4;
    float* dinv   = (float*)w;               w += (size_t)N * 4;
    int*   eidx   = (int*)w;                 w += (size_t)E * 4;
    float* X      = (float*)w;               w += (size_t)N * 64 * 4;
    float* H      = (float*)w;
    float* out    = (float*)d_out;

    const int T  = 256;
    const int NB = (N + T - 1) / T;  // 391

    // ---- CSR build + norm ---------------------------------------------------
    zero_i32_kernel<<<NB, T, 0, stream>>>(cnt, N);
    hist_kernel<<<(E + T - 1) / T, T, 0, stream>>>(col, cnt, E);
    dinv_kernel<<<NB, T, 0, stream>>>(cnt, dinv, N);
    block_reduce_kernel<<<NB, T, 0, stream>>>(cnt, bsum, N);
    scan_bsums_kernel<<<1, 512, 0, stream>>>(bsum, NB);
    scan_kernel<<<NB, T, 0, stream>>>(cnt, bsum, offs, N);
    copy_i32_kernel<<<NB, T, 0, stream>>>(offs, cursor, N);
    scatter_kernel<<<(E + T - 1) / T, T, 0, stream>>>(row, col, cursor, eidx, E);

    const int g64  = (N + 3) / 4;   // gemm blocks, 4 rows/block (SUB=64)
    const int g32  = (N + 7) / 8;   // gemm blocks, 8 rows/block (SUB=32)
    const int a64  = (N * 64 + T - 1) / T;  // agg blocks, 4 nodes/block
    const int a32  = (N * 32 + T - 1) / T;  // agg blocks, 8 nodes/block

    // ---- layer 1: x[128] -> 64 ---------------------------------------------
    gemm_kernel<128, 64, false><<<g64, T, 0, stream>>>(x, W1, dinv, H, N);
    agg_csr_kernel<64><<<a64, T, 0, stream>>>(H, offs, eidx, dinv, b1, X, N);
    // ---- layer 2 ------------------------------------------------------------
    gemm_kernel<64, 64, true><<<g64, T, 0, stream>>>(X, W2, dinv, H, N);
    agg_csr_kernel<64><<<a64, T, 0, stream>>>(H, offs, eidx, dinv, b2, X, N);
    // ---- layer 3 ------------------------------------------------------------
    gemm_kernel<64, 64, true><<<g64, T, 0, stream>>>(X, W3, dinv, H, N);
    agg_csr_kernel<64><<<a64, T, 0, stream>>>(H, offs, eidx, dinv, b3, X, N);
    // ---- layer 4: 64 -> 32, no ReLU, straight to d_out ----------------------
    gemm_kernel<64, 32, true><<<g32, T, 0, stream>>>(X, W4, dinv, H, N);
    agg_csr_kernel<32><<<a32, T, 0, stream>>>(H, offs, eidx, dinv, b4, out, N);
}

// Round 3
// 696.993 us; speedup vs baseline: 2.4944x; 1.3531x over previous
//
#include <hip/hip_runtime.h>

// ---------------------------------------------------------------------------
// GCN forward, CSR-based. N=100000 nodes, E=1600000 edges.
//   build CSR by destination (once):  cnt -> scan -> scatter
//   per layer:  H = (relu?)(X) @ W * dinv[row]        (gemm_tile_kernel)
//               X[c] = b + dinv[c]*(sum_{r in N(c)} H[r] + H[c])   (agg_csr)
// ---------------------------------------------------------------------------

__global__ __launch_bounds__(256) void zero_i32_kernel(int* __restrict__ p, int n) {
    int i = blockIdx.x * blockDim.x + threadIdx.x;
    if (i < n) p[i] = 0;
}

__global__ __launch_bounds__(256) void hist_kernel(const int* __restrict__ col,
                                                   int* __restrict__ cnt, int E) {
    int e = blockIdx.x * blockDim.x + threadIdx.x;
    if (e < E) atomicAdd(&cnt[col[e]], 1);
}

__global__ __launch_bounds__(256) void dinv_kernel(const int* __restrict__ cnt,
                                                   float* __restrict__ dinv, int N) {
    int i = blockIdx.x * blockDim.x + threadIdx.x;
    if (i < N) dinv[i] = rsqrtf((float)cnt[i] + 1.0f);  // +1 self-loop
}

__global__ __launch_bounds__(256) void block_reduce_kernel(const int* __restrict__ cnt,
                                                           int* __restrict__ bsum, int N) {
    __shared__ int s[256];
    int i = blockIdx.x * 256 + threadIdx.x;
    s[threadIdx.x] = (i < N) ? cnt[i] : 0;
    __syncthreads();
    for (int off = 128; off > 0; off >>= 1) {
        if (threadIdx.x < off) s[threadIdx.x] += s[threadIdx.x + off];
        __syncthreads();
    }
    if (threadIdx.x == 0) bsum[blockIdx.x] = s[0];
}

// single block of 512 threads, exclusive-scans bsum in place (nb <= 512)
__global__ __launch_bounds__(512) void scan_bsums_kernel(int* __restrict__ bsum, int nb) {
    __shared__ int s[512];
    int tid = threadIdx.x;
    int v = (tid < nb) ? bsum[tid] : 0;
    s[tid] = v;
    __syncthreads();
    for (int off = 1; off < 512; off <<= 1) {
        int t = (tid >= off) ? s[tid - off] : 0;
        __syncthreads();
        s[tid] += t;
        __syncthreads();
    }
    if (tid < nb) bsum[tid] = s[tid] - v;  // exclusive
}

__global__ __launch_bounds__(256) void scan_kernel(const int* __restrict__ cnt,
                                                   const int* __restrict__ bsum,
                                                   int* __restrict__ offs, int N) {
    __shared__ int s[256];
    int i = blockIdx.x * 256 + threadIdx.x;
    int v = (i < N) ? cnt[i] : 0;
    s[threadIdx.x] = v;
    __syncthreads();
    for (int off = 1; off < 256; off <<= 1) {
        int t = (threadIdx.x >= off) ? s[threadIdx.x - off] : 0;
        __syncthreads();
        s[threadIdx.x] += t;
        __syncthreads();
    }
    int excl = s[threadIdx.x] - v + bsum[blockIdx.x];
    if (i < N) offs[i] = excl;
    if (i == N - 1) offs[N] = excl + v;
}

__global__ __launch_bounds__(256) void copy_i32_kernel(const int* __restrict__ src,
                                                       int* __restrict__ dst, int n) {
    int i = blockIdx.x * blockDim.x + threadIdx.x;
    if (i < n) dst[i] = src[i];
}

__global__ __launch_bounds__(256) void scatter_kernel(const int* __restrict__ row,
                                                      const int* __restrict__ col,
                                                      int* __restrict__ cursor,
                                                      int* __restrict__ eidx, int E) {
    int e = blockIdx.x * blockDim.x + threadIdx.x;
    if (e < E) {
        int pos = atomicAdd(&cursor[col[e]], 1);
        eidx[pos] = row[e];
    }
}

// H = ((RELU? relu(in) : in) @ W) * dinv[row].   W is [F_IN, F_OUT] row-major.
// Register-tiled: block covers ROWS x F_OUT outputs, thread computes 4x4.
// sIn padded to 68 floats/row: keeps 16B alignment, rows hit distinct bank
// groups (2-way max = free per m136).
template <int F_IN, int F_OUT, bool RELU>
__global__ __launch_bounds__(256) void gemm_tile_kernel(const float* __restrict__ in,
                                                        const float* __restrict__ W,
                                                        const float* __restrict__ dinv,
                                                        float* __restrict__ out, int N) {
    constexpr int TC   = F_OUT / 4;   // col-thread groups (16 or 8)
    constexpr int TR   = 256 / TC;    // row-thread groups (16 or 32)
    constexpr int ROWS = TR * 4;      // rows per block (64 or 128)
    constexpr int NKB  = F_IN / 64;   // k-blocks of 64
    __shared__ float sIn[ROWS][68];
    __shared__ float sW[64][F_OUT];

    const int tc = threadIdx.x % TC;
    const int tr = threadIdx.x / TC;
    const int r0 = blockIdx.x * ROWS;

    float acc[4][4] = {};

#pragma unroll
    for (int kb = 0; kb < NKB; ++kb) {
        if (kb) __syncthreads();
        // stage input tile (coalesced float4 loads, ReLU fused)
        for (int idx = threadIdx.x; idx < ROWS * 16; idx += 256) {
            int rr = idx / 16, c4 = (idx % 16) * 4;
            int gr = min(r0 + rr, N - 1);
            float4 v = *(const float4*)&in[(size_t)gr * F_IN + kb * 64 + c4];
            if (RELU) {
                v.x = fmaxf(v.x, 0.f); v.y = fmaxf(v.y, 0.f);
                v.z = fmaxf(v.z, 0.f); v.w = fmaxf(v.w, 0.f);
            }
            *(float4*)&sIn[rr][c4] = v;
        }
        // stage W k-block
        for (int idx = threadIdx.x; idx < 64 * F_OUT / 4; idx += 256) {
            int kr = idx / (F_OUT / 4), c4 = (idx % (F_OUT / 4)) * 4;
            *(float4*)&sW[kr][c4] = *(const float4*)&W[(size_t)(kb * 64 + kr) * F_OUT + c4];
        }
        __syncthreads();
#pragma unroll
        for (int kk = 0; kk < 64; kk += 4) {
            float4 iv[4], wv[4];
#pragma unroll
            for (int i = 0; i < 4; ++i) iv[i] = *(const float4*)&sIn[tr * 4 + i][kk];
#pragma unroll
            for (int q = 0; q < 4; ++q) wv[q] = *(const float4*)&sW[kk + q][tc * 4];
#pragma unroll
            for (int i = 0; i < 4; ++i) {
                const float ik[4] = {iv[i].x, iv[i].y, iv[i].z, iv[i].w};
#pragma unroll
                for (int q = 0; q < 4; ++q) {
                    acc[i][0] = fmaf(ik[q], wv[q].x, acc[i][0]);
                    acc[i][1] = fmaf(ik[q], wv[q].y, acc[i][1]);
                    acc[i][2] = fmaf(ik[q], wv[q].z, acc[i][2]);
                    acc[i][3] = fmaf(ik[q], wv[q].w, acc[i][3]);
                }
            }
        }
    }
#pragma unroll
    for (int i = 0; i < 4; ++i) {
        int r = r0 + tr * 4 + i;
        if (r < N) {
            float d = dinv[r];
            float4 v = {acc[i][0] * d, acc[i][1] * d, acc[i][2] * d, acc[i][3] * d};
            *(float4*)&out[(size_t)r * F_OUT + tc * 4] = v;
        }
    }
}

// out[c, j] = b[j] + dinv[c] * ( sum_{k in [offs[c],offs[c+1])} H[eidx[k], j] + H[c, j] )
template <int F>
__global__ __launch_bounds__(256) void agg_csr_kernel(const float* __restrict__ h,
                                                      const int* __restrict__ offs,
                                                      const int* __restrict__ eidx,
                                                      const float* __restrict__ dinv,
                                                      const float* __restrict__ b,
                                                      float* __restrict__ out, int N) {
    int seg = (blockIdx.x * 256 + threadIdx.x) / F;  // destination node
    int j   = threadIdx.x % F;
    if (seg >= N) return;
    int s = offs[seg];
    int e = offs[seg + 1];

    float a0 = 0.f, a1 = 0.f, a2 = 0.f, a3 = 0.f;
    int k = s;
    for (; k + 4 <= e; k += 4) {
        int r0 = eidx[k], r1 = eidx[k + 1], r2 = eidx[k + 2], r3 = eidx[k + 3];
        a0 += h[(size_t)r0 * F + j];
        a1 += h[(size_t)r1 * F + j];
        a2 += h[(size_t)r2 * F + j];
        a3 += h[(size_t)r3 * F + j];
    }
    for (; k < e; ++k) a0 += h[(size_t)eidx[k] * F + j];

    float acc  = (a0 + a1) + (a2 + a3);
    float self = h[(size_t)seg * F + j];
    out[(size_t)seg * F + j] = b[j] + dinv[seg] * (acc + self);
}

extern "C" void kernel_launch(void* const* d_in, const int* in_sizes, int n_in,
                              void* d_out, int out_size, void* d_ws, size_t ws_size,
                              hipStream_t stream) {
    const float* x  = (const float*)d_in[0];
    const int*   ei = (const int*)d_in[1];
    const float* W1 = (const float*)d_in[2];
    const float* b1 = (const float*)d_in[3];
    const float* W2 = (const float*)d_in[4];
    const float* b2 = (const float*)d_in[5];
    const float* W3 = (const float*)d_in[6];
    const float* b3 = (const float*)d_in[7];
    const float* W4 = (const float*)d_in[8];
    const float* b4 = (const float*)d_in[9];

    const int N = in_sizes[0] / 128;  // 100000
    const int E = in_sizes[1] / 2;    // 1600000
    const int* row = ei;              // source
    const int* col = ei + E;          // destination

    // ---- workspace layout ---------------------------------------------------
    char* w = (char*)d_ws;
    int*   cnt    = (int*)w;                 w += (size_t)N * 4;
    int*   offs   = (int*)w;                 w += (size_t)(N + 1) * 4;
    int*   cursor = (int*)w;                 w += (size_t)N * 4;
    int*   bsum   = (int*)w;                 w += 512 * 4;
    float* dinv   = (float*)w;               w += (size_t)N * 4;
    int*   eidx   = (int*)w;                 w += (size_t)E * 4;
    float* X      = (float*)w;               w += (size_t)N * 64 * 4;
    float* H      = (float*)w;
    float* out    = (float*)d_out;

    const int T  = 256;
    const int NB = (N + T - 1) / T;  // 391

    // ---- CSR build + norm ---------------------------------------------------
    zero_i32_kernel<<<NB, T, 0, stream>>>(cnt, N);
    hist_kernel<<<(E + T - 1) / T, T, 0, stream>>>(col, cnt, E);
    dinv_kernel<<<NB, T, 0, stream>>>(cnt, dinv, N);
    block_reduce_kernel<<<NB, T, 0, stream>>>(cnt, bsum, N);
    scan_bsums_kernel<<<1, 512, 0, stream>>>(bsum, NB);
    scan_kernel<<<NB, T, 0, stream>>>(cnt, bsum, offs, N);
    copy_i32_kernel<<<NB, T, 0, stream>>>(offs, cursor, N);
    scatter_kernel<<<(E + T - 1) / T, T, 0, stream>>>(row, col, cursor, eidx, E);

    const int g64 = (N + 63) / 64;    // gemm blocks, 64 rows/block (F_OUT=64)
    const int g32 = (N + 127) / 128;  // gemm blocks, 128 rows/block (F_OUT=32)
    const int a64 = (N * 64 + T - 1) / T;  // agg blocks, 4 nodes/block
    const int a32 = (N * 32 + T - 1) / T;  // agg blocks, 8 nodes/block

    // ---- layer 1: x[128] -> 64 ---------------------------------------------
    gemm_tile_kernel<128, 64, false><<<g64, T, 0, stream>>>(x, W1, dinv, H, N);
    agg_csr_kernel<64><<<a64, T, 0, stream>>>(H, offs, eidx, dinv, b1, X, N);
    // ---- layer 2 ------------------------------------------------------------
    gemm_tile_kernel<64, 64, true><<<g64, T, 0, stream>>>(X, W2, dinv, H, N);
    agg_csr_kernel<64><<<a64, T, 0, stream>>>(H, offs, eidx, dinv, b2, X, N);
    // ---- layer 3 ------------------------------------------------------------
    gemm_tile_kernel<64, 64, true><<<g64, T, 0, stream>>>(X, W3, dinv, H, N);
    agg_csr_kernel<64><<<a64, T, 0, stream>>>(H, offs, eidx, dinv, b3, X, N);
    // ---- layer 4: 64 -> 32, no ReLU, straight to d_out ----------------------
    gemm_tile_kernel<64, 32, true><<<g32, T, 0, stream>>>(X, W4, dinv, H, N);
    agg_csr_kernel<32><<<a32, T, 0, stream>>>(H, offs, eidx, dinv, b4, out, N);
}

// Round 4
// 635.236 us; speedup vs baseline: 2.7369x; 1.0972x over previous
//
#include <hip/hip_runtime.h>

// ---------------------------------------------------------------------------
// GCN forward, CSR-based. N=100000 nodes, E=1600000 edges.
//   build CSR by destination (once):  cnt -> scan -> XCD-partitioned scatter
//   per layer:  H = (relu?)(X) @ W * dinv[row]        (gemm_tile_kernel)
//               X[c] = b + dinv[c]*(sum_{r in N(c)} H[r] + H[c])   (agg_csr)
// ---------------------------------------------------------------------------

__device__ inline void f4acc(float4& a, const float4 v) {
    a.x += v.x; a.y += v.y; a.z += v.z; a.w += v.w;
}

__global__ __launch_bounds__(256) void zero_i32_kernel(int* __restrict__ p, int n) {
    int i = blockIdx.x * blockDim.x + threadIdx.x;
    if (i < n) p[i] = 0;
}

__global__ __launch_bounds__(256) void hist_kernel(const int* __restrict__ col,
                                                   int* __restrict__ cnt, int E) {
    int e = blockIdx.x * blockDim.x + threadIdx.x;
    if (e < E) atomicAdd(&cnt[col[e]], 1);
}

__global__ __launch_bounds__(256) void dinv_kernel(const int* __restrict__ cnt,
                                                   float* __restrict__ dinv, int N) {
    int i = blockIdx.x * blockDim.x + threadIdx.x;
    if (i < N) dinv[i] = rsqrtf((float)cnt[i] + 1.0f);  // +1 self-loop
}

__global__ __launch_bounds__(256) void block_reduce_kernel(const int* __restrict__ cnt,
                                                           int* __restrict__ bsum, int N) {
    __shared__ int s[256];
    int i = blockIdx.x * 256 + threadIdx.x;
    s[threadIdx.x] = (i < N) ? cnt[i] : 0;
    __syncthreads();
    for (int off = 128; off > 0; off >>= 1) {
        if (threadIdx.x < off) s[threadIdx.x] += s[threadIdx.x + off];
        __syncthreads();
    }
    if (threadIdx.x == 0) bsum[blockIdx.x] = s[0];
}

// single block of 512 threads, exclusive-scans bsum in place (nb <= 512)
__global__ __launch_bounds__(512) void scan_bsums_kernel(int* __restrict__ bsum, int nb) {
    __shared__ int s[512];
    int tid = threadIdx.x;
    int v = (tid < nb) ? bsum[tid] : 0;
    s[tid] = v;
    __syncthreads();
    for (int off = 1; off < 512; off <<= 1) {
        int t = (tid >= off) ? s[tid - off] : 0;
        __syncthreads();
        s[tid] += t;
        __syncthreads();
    }
    if (tid < nb) bsum[tid] = s[tid] - v;  // exclusive
}

__global__ __launch_bounds__(256) void scan_kernel(const int* __restrict__ cnt,
                                                   const int* __restrict__ bsum,
                                                   int* __restrict__ offs, int N) {
    __shared__ int s[256];
    int i = blockIdx.x * 256 + threadIdx.x;
    int v = (i < N) ? cnt[i] : 0;
    s[threadIdx.x] = v;
    __syncthreads();
    for (int off = 1; off < 256; off <<= 1) {
        int t = (threadIdx.x >= off) ? s[threadIdx.x - off] : 0;
        __syncthreads();
        s[threadIdx.x] += t;
        __syncthreads();
    }
    int excl = s[threadIdx.x] - v + bsum[blockIdx.x];
    if (i < N) offs[i] = excl;
    if (i == N - 1) offs[N] = excl + v;
}

__global__ __launch_bounds__(256) void copy_i32_kernel(const int* __restrict__ src,
                                                       int* __restrict__ dst, int n) {
    int i = blockIdx.x * blockDim.x + threadIdx.x;
    if (i < n) dst[i] = src[i];
}

// XCD-partitioned scatter: blocks with (blockIdx & 7) == p handle only edges
// whose destination lies in partition p's node range. Each eidx/cursor line is
// then written by a single XCD -> lines fill fully in that L2 before
// write-back (kills the 16x write amplification of the naive scatter).
// Mapping blockIdx%8 -> XCD is a perf heuristic only; correctness holds
// regardless of dispatch order.
__global__ __launch_bounds__(256) void scatter_part_kernel(const int* __restrict__ row,
                                                           const int* __restrict__ col,
                                                           int* __restrict__ cursor,
                                                           int* __restrict__ eidx,
                                                           int E, int span) {
    const int part = blockIdx.x & 7;
    const int lo = part * span, hi = lo + span;
    const int nwg = gridDim.x >> 3;
    const int wg  = blockIdx.x >> 3;
    for (int e = wg * 256 + threadIdx.x; e < E; e += nwg * 256) {
        int c = col[e];
        if (c >= lo && c < hi) {
            int pos = atomicAdd(&cursor[c], 1);
            eidx[pos] = row[e];
        }
    }
}

// H = ((RELU? relu(in) : in) @ W) * dinv[row].   W is [F_IN, F_OUT] row-major.
template <int F_IN, int F_OUT, bool RELU>
__global__ __launch_bounds__(256) void gemm_tile_kernel(const float* __restrict__ in,
                                                        const float* __restrict__ W,
                                                        const float* __restrict__ dinv,
                                                        float* __restrict__ out, int N) {
    constexpr int TC   = F_OUT / 4;   // col-thread groups (16 or 8)
    constexpr int TR   = 256 / TC;    // row-thread groups (16 or 32)
    constexpr int ROWS = TR * 4;      // rows per block (64 or 128)
    constexpr int NKB  = F_IN / 64;   // k-blocks of 64
    __shared__ float sIn[ROWS][68];
    __shared__ float sW[64][F_OUT];

    const int tc = threadIdx.x % TC;
    const int tr = threadIdx.x / TC;
    const int r0 = blockIdx.x * ROWS;

    float acc[4][4] = {};

#pragma unroll
    for (int kb = 0; kb < NKB; ++kb) {
        if (kb) __syncthreads();
        for (int idx = threadIdx.x; idx < ROWS * 16; idx += 256) {
            int rr = idx / 16, c4 = (idx % 16) * 4;
            int gr = min(r0 + rr, N - 1);
            float4 v = *(const float4*)&in[(size_t)gr * F_IN + kb * 64 + c4];
            if (RELU) {
                v.x = fmaxf(v.x, 0.f); v.y = fmaxf(v.y, 0.f);
                v.z = fmaxf(v.z, 0.f); v.w = fmaxf(v.w, 0.f);
            }
            *(float4*)&sIn[rr][c4] = v;
        }
        for (int idx = threadIdx.x; idx < 64 * F_OUT / 4; idx += 256) {
            int kr = idx / (F_OUT / 4), c4 = (idx % (F_OUT / 4)) * 4;
            *(float4*)&sW[kr][c4] = *(const float4*)&W[(size_t)(kb * 64 + kr) * F_OUT + c4];
        }
        __syncthreads();
#pragma unroll
        for (int kk = 0; kk < 64; kk += 4) {
            float4 iv[4], wv[4];
#pragma unroll
            for (int i = 0; i < 4; ++i) iv[i] = *(const float4*)&sIn[tr * 4 + i][kk];
#pragma unroll
            for (int q = 0; q < 4; ++q) wv[q] = *(const float4*)&sW[kk + q][tc * 4];
#pragma unroll
            for (int i = 0; i < 4; ++i) {
                const float ik[4] = {iv[i].x, iv[i].y, iv[i].z, iv[i].w};
#pragma unroll
                for (int q = 0; q < 4; ++q) {
                    acc[i][0] = fmaf(ik[q], wv[q].x, acc[i][0]);
                    acc[i][1] = fmaf(ik[q], wv[q].y, acc[i][1]);
                    acc[i][2] = fmaf(ik[q], wv[q].z, acc[i][2]);
                    acc[i][3] = fmaf(ik[q], wv[q].w, acc[i][3]);
                }
            }
        }
    }
#pragma unroll
    for (int i = 0; i < 4; ++i) {
        int r = r0 + tr * 4 + i;
        if (r < N) {
            float d = dinv[r];
            float4 v = {acc[i][0] * d, acc[i][1] * d, acc[i][2] * d, acc[i][3] * d};
            *(float4*)&out[(size_t)r * F_OUT + tc * 4] = v;
        }
    }
}

// out[c, j4..j4+3] = b + dinv[c] * ( sum_{neighbors} H[r] + H[c] ), float4 lanes.
// F/4 lanes per destination node: 4-deep unrolled float4 gathers (16B/lane).
template <int F>
__global__ __launch_bounds__(256) void agg_csr_kernel(const float* __restrict__ h,
                                                      const int* __restrict__ offs,
                                                      const int* __restrict__ eidx,
                                                      const float* __restrict__ dinv,
                                                      const float* __restrict__ b,
                                                      float* __restrict__ out, int N) {
    constexpr int L = F / 4;  // lanes per node (16 or 8)
    int seg = (blockIdx.x * 256 + threadIdx.x) / L;
    int j4  = (threadIdx.x % L) * 4;
    if (seg >= N) return;
    int s = offs[seg];
    int e = offs[seg + 1];

    float4 a0 = {0.f, 0.f, 0.f, 0.f}, a1 = a0, a2 = a0, a3 = a0;
    int k = s;
    for (; k + 4 <= e; k += 4) {
        int r0 = eidx[k], r1 = eidx[k + 1], r2 = eidx[k + 2], r3 = eidx[k + 3];
        f4acc(a0, *(const float4*)&h[(size_t)r0 * F + j4]);
        f4acc(a1, *(const float4*)&h[(size_t)r1 * F + j4]);
        f4acc(a2, *(const float4*)&h[(size_t)r2 * F + j4]);
        f4acc(a3, *(const float4*)&h[(size_t)r3 * F + j4]);
    }
    for (; k < e; ++k) f4acc(a0, *(const float4*)&h[(size_t)eidx[k] * F + j4]);

    f4acc(a0, a1); f4acc(a2, a3); f4acc(a0, a2);
    f4acc(a0, *(const float4*)&h[(size_t)seg * F + j4]);  // self-loop
    float4 bv = *(const float4*)&b[j4];
    float  d  = dinv[seg];
    float4 o  = {bv.x + d * a0.x, bv.y + d * a0.y, bv.z + d * a0.z, bv.w + d * a0.w};
    *(float4*)&out[(size_t)seg * F + j4] = o;
}

extern "C" void kernel_launch(void* const* d_in, const int* in_sizes, int n_in,
                              void* d_out, int out_size, void* d_ws, size_t ws_size,
                              hipStream_t stream) {
    const float* x  = (const float*)d_in[0];
    const int*   ei = (const int*)d_in[1];
    const float* W1 = (const float*)d_in[2];
    const float* b1 = (const float*)d_in[3];
    const float* W2 = (const float*)d_in[4];
    const float* b2 = (const float*)d_in[5];
    const float* W3 = (const float*)d_in[6];
    const float* b3 = (const float*)d_in[7];
    const float* W4 = (const float*)d_in[8];
    const float* b4 = (const float*)d_in[9];

    const int N = in_sizes[0] / 128;  // 100000
    const int E = in_sizes[1] / 2;    // 1600000
    const int* row = ei;              // source
    const int* col = ei + E;          // destination

    // ---- workspace layout ---------------------------------------------------
    char* w = (char*)d_ws;
    int*   cnt    = (int*)w;                 w += (size_t)N * 4;
    int*   offs   = (int*)w;                 w += (size_t)(N + 1) * 4;
    int*   cursor = (int*)w;                 w += (size_t)N * 4;
    int*   bsum   = (int*)w;                 w += 512 * 4;
    float* dinv   = (float*)w;               w += (size_t)N * 4;
    int*   eidx   = (int*)w;                 w += (size_t)E * 4;
    float* X      = (float*)w;               w += (size_t)N * 64 * 4;
    float* H      = (float*)w;
    float* out    = (float*)d_out;

    const int T  = 256;
    const int NB = (N + T - 1) / T;  // 391

    // ---- CSR build + norm ---------------------------------------------------
    zero_i32_kernel<<<NB, T, 0, stream>>>(cnt, N);
    hist_kernel<<<(E + T - 1) / T, T, 0, stream>>>(col, cnt, E);
    dinv_kernel<<<NB, T, 0, stream>>>(cnt, dinv, N);
    block_reduce_kernel<<<NB, T, 0, stream>>>(cnt, bsum, N);
    scan_bsums_kernel<<<1, 512, 0, stream>>>(bsum, NB);
    scan_kernel<<<NB, T, 0, stream>>>(cnt, bsum, offs, N);
    copy_i32_kernel<<<NB, T, 0, stream>>>(offs, cursor, N);
    scatter_part_kernel<<<2048, T, 0, stream>>>(row, col, cursor, eidx, E, (N + 7) / 8);

    const int g64 = (N + 63) / 64;    // gemm blocks, 64 rows/block (F_OUT=64)
    const int g32 = (N + 127) / 128;  // gemm blocks, 128 rows/block (F_OUT=32)
    const int a64 = (N * 16 + T - 1) / T;  // agg blocks, 16 lanes/node
    const int a32 = (N * 8 + T - 1) / T;   // agg blocks, 8 lanes/node

    // ---- layer 1: x[128] -> 64 ---------------------------------------------
    gemm_tile_kernel<128, 64, false><<<g64, T, 0, stream>>>(x, W1, dinv, H, N);
    agg_csr_kernel<64><<<a64, T, 0, stream>>>(H, offs, eidx, dinv, b1, X, N);
    // ---- layer 2 ------------------------------------------------------------
    gemm_tile_kernel<64, 64, true><<<g64, T, 0, stream>>>(X, W2, dinv, H, N);
    agg_csr_kernel<64><<<a64, T, 0, stream>>>(H, offs, eidx, dinv, b2, X, N);
    // ---- layer 3 ------------------------------------------------------------
    gemm_tile_kernel<64, 64, true><<<g64, T, 0, stream>>>(X, W3, dinv, H, N);
    agg_csr_kernel<64><<<a64, T, 0, stream>>>(H, offs, eidx, dinv, b3, X, N);
    // ---- layer 4: 64 -> 32, no ReLU, straight to d_out ----------------------
    gemm_tile_kernel<64, 32, true><<<g32, T, 0, stream>>>(X, W4, dinv, H, N);
    agg_csr_kernel<32><<<a32, T, 0, stream>>>(H, offs, eidx, dinv, b4, out, N);
}

// Round 5
// 536.371 us; speedup vs baseline: 3.2414x; 1.1843x over previous
//
#include <hip/hip_runtime.h>

// ---------------------------------------------------------------------------
// GCN forward, CSR-based. N=100000 nodes, E=1600000 edges.
//   build CSR by destination (once):  cnt -> scan -> XCD-partitioned scatter
//   per layer:  H = (relu?)(X) @ W * dinv[row]        (gemm_tile_kernel)
//               X[c] = b + dinv[c]*(sum_{r in N(c)} H[r] + H[c])   (agg_csr)
// ---------------------------------------------------------------------------

__device__ inline void f4acc(float4& a, const float4 v) {
    a.x += v.x; a.y += v.y; a.z += v.z; a.w += v.w;
}

__global__ __launch_bounds__(256) void zero_i32_kernel(int* __restrict__ p, int n) {
    int i = blockIdx.x * blockDim.x + threadIdx.x;
    if (i < n) p[i] = 0;
}

__global__ __launch_bounds__(256) void hist_kernel(const int* __restrict__ col,
                                                   int* __restrict__ cnt, int E) {
    int e = blockIdx.x * blockDim.x + threadIdx.x;
    if (e < E) atomicAdd(&cnt[col[e]], 1);
}

__global__ __launch_bounds__(256) void dinv_kernel(const int* __restrict__ cnt,
                                                   float* __restrict__ dinv, int N) {
    int i = blockIdx.x * blockDim.x + threadIdx.x;
    if (i < N) dinv[i] = rsqrtf((float)cnt[i] + 1.0f);  // +1 self-loop
}

__global__ __launch_bounds__(256) void block_reduce_kernel(const int* __restrict__ cnt,
                                                           int* __restrict__ bsum, int N) {
    __shared__ int s[256];
    int i = blockIdx.x * 256 + threadIdx.x;
    s[threadIdx.x] = (i < N) ? cnt[i] : 0;
    __syncthreads();
    for (int off = 128; off > 0; off >>= 1) {
        if (threadIdx.x < off) s[threadIdx.x] += s[threadIdx.x + off];
        __syncthreads();
    }
    if (threadIdx.x == 0) bsum[blockIdx.x] = s[0];
}

// single block of 512 threads, exclusive-scans bsum in place (nb <= 512)
__global__ __launch_bounds__(512) void scan_bsums_kernel(int* __restrict__ bsum, int nb) {
    __shared__ int s[512];
    int tid = threadIdx.x;
    int v = (tid < nb) ? bsum[tid] : 0;
    s[tid] = v;
    __syncthreads();
    for (int off = 1; off < 512; off <<= 1) {
        int t = (tid >= off) ? s[tid - off] : 0;
        __syncthreads();
        s[tid] += t;
        __syncthreads();
    }
    if (tid < nb) bsum[tid] = s[tid] - v;  // exclusive
}

__global__ __launch_bounds__(256) void scan_kernel(const int* __restrict__ cnt,
                                                   const int* __restrict__ bsum,
                                                   int* __restrict__ offs, int N) {
    __shared__ int s[256];
    int i = blockIdx.x * 256 + threadIdx.x;
    int v = (i < N) ? cnt[i] : 0;
    s[threadIdx.x] = v;
    __syncthreads();
    for (int off = 1; off < 256; off <<= 1) {
        int t = (threadIdx.x >= off) ? s[threadIdx.x - off] : 0;
        __syncthreads();
        s[threadIdx.x] += t;
        __syncthreads();
    }
    int excl = s[threadIdx.x] - v + bsum[blockIdx.x];
    if (i < N) offs[i] = excl;
    if (i == N - 1) offs[N] = excl + v;
}

__global__ __launch_bounds__(256) void copy_i32_kernel(const int* __restrict__ src,
                                                       int* __restrict__ dst, int n) {
    int i = blockIdx.x * blockDim.x + threadIdx.x;
    if (i < n) dst[i] = src[i];
}

// XCD-partitioned scatter: blocks with (blockIdx & 7) == p handle only edges
// whose destination lies in partition p's node range (kills cross-XCD line
// thrash on eidx writes; see round-3 -> round-4 WRITE_SIZE drop).
__global__ __launch_bounds__(256) void scatter_part_kernel(const int* __restrict__ row,
                                                           const int* __restrict__ col,
                                                           int* __restrict__ cursor,
                                                           int* __restrict__ eidx,
                                                           int E, int span) {
    const int part = blockIdx.x & 7;
    const int lo = part * span, hi = lo + span;
    const int nwg = gridDim.x >> 3;
    const int wg  = blockIdx.x >> 3;
    for (int e = wg * 256 + threadIdx.x; e < E; e += nwg * 256) {
        int c = col[e];
        if (c >= lo && c < hi) {
            int pos = atomicAdd(&cursor[c], 1);
            eidx[pos] = row[e];
        }
    }
}

// H = ((RELU? relu(in) : in) @ W) * dinv[row].   W is [F_IN, F_OUT] row-major.
// __launch_bounds__(256,4): cap VGPR at 128 -> 16 waves/CU (round-4 profile
// showed 248 VGPR / 9.6% occupancy = latency-bound). Inner unroll capped at 2
// to keep ~92 live regs (no scratch spill).
template <int F_IN, int F_OUT, bool RELU>
__global__ __launch_bounds__(256, 4) void gemm_tile_kernel(const float* __restrict__ in,
                                                           const float* __restrict__ W,
                                                           const float* __restrict__ dinv,
                                                           float* __restrict__ out, int N) {
    constexpr int TC   = F_OUT / 4;   // col-thread groups (16 or 8)
    constexpr int TR   = 256 / TC;    // row-thread groups (16 or 32)
    constexpr int ROWS = TR * 4;      // rows per block (64 or 128)
    constexpr int NKB  = F_IN / 64;   // k-blocks of 64
    __shared__ float sIn[ROWS][68];
    __shared__ float sW[64][F_OUT];

    const int tc = threadIdx.x % TC;
    const int tr = threadIdx.x / TC;
    const int r0 = blockIdx.x * ROWS;

    float acc[4][4] = {};

#pragma unroll
    for (int kb = 0; kb < NKB; ++kb) {
        if (kb) __syncthreads();
        for (int idx = threadIdx.x; idx < ROWS * 16; idx += 256) {
            int rr = idx / 16, c4 = (idx % 16) * 4;
            int gr = min(r0 + rr, N - 1);
            float4 v = *(const float4*)&in[(size_t)gr * F_IN + kb * 64 + c4];
            if (RELU) {
                v.x = fmaxf(v.x, 0.f); v.y = fmaxf(v.y, 0.f);
                v.z = fmaxf(v.z, 0.f); v.w = fmaxf(v.w, 0.f);
            }
            *(float4*)&sIn[rr][c4] = v;
        }
        for (int idx = threadIdx.x; idx < 64 * F_OUT / 4; idx += 256) {
            int kr = idx / (F_OUT / 4), c4 = (idx % (F_OUT / 4)) * 4;
            *(float4*)&sW[kr][c4] = *(const float4*)&W[(size_t)(kb * 64 + kr) * F_OUT + c4];
        }
        __syncthreads();
#pragma unroll 2
        for (int kk = 0; kk < 64; kk += 4) {
            float4 iv[4], wv[4];
#pragma unroll
            for (int i = 0; i < 4; ++i) iv[i] = *(const float4*)&sIn[tr * 4 + i][kk];
#pragma unroll
            for (int q = 0; q < 4; ++q) wv[q] = *(const float4*)&sW[kk + q][tc * 4];
#pragma unroll
            for (int i = 0; i < 4; ++i) {
                const float ik[4] = {iv[i].x, iv[i].y, iv[i].z, iv[i].w};
#pragma unroll
                for (int q = 0; q < 4; ++q) {
                    acc[i][0] = fmaf(ik[q], wv[q].x, acc[i][0]);
                    acc[i][1] = fmaf(ik[q], wv[q].y, acc[i][1]);
                    acc[i][2] = fmaf(ik[q], wv[q].z, acc[i][2]);
                    acc[i][3] = fmaf(ik[q], wv[q].w, acc[i][3]);
                }
            }
        }
    }
#pragma unroll
    for (int i = 0; i < 4; ++i) {
        int r = r0 + tr * 4 + i;
        if (r < N) {
            float d = dinv[r];
            float4 v = {acc[i][0] * d, acc[i][1] * d, acc[i][2] * d, acc[i][3] * d};
            *(float4*)&out[(size_t)r * F_OUT + tc * 4] = v;
        }
    }
}

// out[c, j4..j4+3] = b + dinv[c] * ( sum_{neighbors} H[r] + H[c] ), float4 lanes.
template <int F>
__global__ __launch_bounds__(256) void agg_csr_kernel(const float* __restrict__ h,
                                                      const int* __restrict__ offs,
                                                      const int* __restrict__ eidx,
                                                      const float* __restrict__ dinv,
                                                      const float* __restrict__ b,
                                                      float* __restrict__ out, int N) {
    constexpr int L = F / 4;  // lanes per node (16 or 8)
    int seg = (blockIdx.x * 256 + threadIdx.x) / L;
    int j4  = (threadIdx.x % L) * 4;
    if (seg >= N) return;
    int s = offs[seg];
    int e = offs[seg + 1];

    float4 a0 = {0.f, 0.f, 0.f, 0.f}, a1 = a0, a2 = a0, a3 = a0;
    int k = s;
    for (; k + 4 <= e; k += 4) {
        int r0 = eidx[k], r1 = eidx[k + 1], r2 = eidx[k + 2], r3 = eidx[k + 3];
        f4acc(a0, *(const float4*)&h[(size_t)r0 * F + j4]);
        f4acc(a1, *(const float4*)&h[(size_t)r1 * F + j4]);
        f4acc(a2, *(const float4*)&h[(size_t)r2 * F + j4]);
        f4acc(a3, *(const float4*)&h[(size_t)r3 * F + j4]);
    }
    for (; k < e; ++k) f4acc(a0, *(const float4*)&h[(size_t)eidx[k] * F + j4]);

    f4acc(a0, a1); f4acc(a2, a3); f4acc(a0, a2);
    f4acc(a0, *(const float4*)&h[(size_t)seg * F + j4]);  // self-loop
    float4 bv = *(const float4*)&b[j4];
    float  d  = dinv[seg];
    float4 o  = {bv.x + d * a0.x, bv.y + d * a0.y, bv.z + d * a0.z, bv.w + d * a0.w};
    *(float4*)&out[(size_t)seg * F + j4] = o;
}

extern "C" void kernel_launch(void* const* d_in, const int* in_sizes, int n_in,
                              void* d_out, int out_size, void* d_ws, size_t ws_size,
                              hipStream_t stream) {
    const float* x  = (const float*)d_in[0];
    const int*   ei = (const int*)d_in[1];
    const float* W1 = (const float*)d_in[2];
    const float* b1 = (const float*)d_in[3];
    const float* W2 = (const float*)d_in[4];
    const float* b2 = (const float*)d_in[5];
    const float* W3 = (const float*)d_in[6];
    const float* b3 = (const float*)d_in[7];
    const float* W4 = (const float*)d_in[8];
    const float* b4 = (const float*)d_in[9];

    const int N = in_sizes[0] / 128;  // 100000
    const int E = in_sizes[1] / 2;    // 1600000
    const int* row = ei;              // source
    const int* col = ei + E;          // destination

    // ---- workspace layout ---------------------------------------------------
    char* w = (char*)d_ws;
    int*   cnt    = (int*)w;                 w += (size_t)N * 4;
    int*   offs   = (int*)w;                 w += (size_t)(N + 1) * 4;
    int*   cursor = (int*)w;                 w += (size_t)N * 4;
    int*   bsum   = (int*)w;                 w += 512 * 4;
    float* dinv   = (float*)w;               w += (size_t)N * 4;
    int*   eidx   = (int*)w;                 w += (size_t)E * 4;
    float* X      = (float*)w;               w += (size_t)N * 64 * 4;
    float* H      = (float*)w;
    float* out    = (float*)d_out;

    const int T  = 256;
    const int NB = (N + T - 1) / T;  // 391

    // ---- CSR build + norm ---------------------------------------------------
    zero_i32_kernel<<<NB, T, 0, stream>>>(cnt, N);
    hist_kernel<<<(E + T - 1) / T, T, 0, stream>>>(col, cnt, E);
    dinv_kernel<<<NB, T, 0, stream>>>(cnt, dinv, N);
    block_reduce_kernel<<<NB, T, 0, stream>>>(cnt, bsum, N);
    scan_bsums_kernel<<<1, 512, 0, stream>>>(bsum, NB);
    scan_kernel<<<NB, T, 0, stream>>>(cnt, bsum, offs, N);
    copy_i32_kernel<<<NB, T, 0, stream>>>(offs, cursor, N);
    scatter_part_kernel<<<2048, T, 0, stream>>>(row, col, cursor, eidx, E, (N + 7) / 8);

    const int g64 = (N + 63) / 64;    // gemm blocks, 64 rows/block (F_OUT=64)
    const int g32 = (N + 127) / 128;  // gemm blocks, 128 rows/block (F_OUT=32)
    const int a64 = (N * 16 + T - 1) / T;  // agg blocks, 16 lanes/node
    const int a32 = (N * 8 + T - 1) / T;   // agg blocks, 8 lanes/node

    // ---- layer 1: x[128] -> 64 ---------------------------------------------
    gemm_tile_kernel<128, 64, false><<<g64, T, 0, stream>>>(x, W1, dinv, H, N);
    agg_csr_kernel<64><<<a64, T, 0, stream>>>(H, offs, eidx, dinv, b1, X, N);
    // ---- layer 2 ------------------------------------------------------------
    gemm_tile_kernel<64, 64, true><<<g64, T, 0, stream>>>(X, W2, dinv, H, N);
    agg_csr_kernel<64><<<a64, T, 0, stream>>>(H, offs, eidx, dinv, b2, X, N);
    // ---- layer 3 ------------------------------------------------------------
    gemm_tile_kernel<64, 64, true><<<g64, T, 0, stream>>>(X, W3, dinv, H, N);
    agg_csr_kernel<64><<<a64, T, 0, stream>>>(H, offs, eidx, dinv, b3, X, N);
    // ---- layer 4: 64 -> 32, no ReLU, straight to d_out ----------------------
    gemm_tile_kernel<64, 32, true><<<g32, T, 0, stream>>>(X, W4, dinv, H, N);
    agg_csr_kernel<32><<<a32, T, 0, stream>>>(H, offs, eidx, dinv, b4, out, N);
}